// Round 1
// baseline (65.499 us; speedup 1.0000x reference)
//
#include <hip/hip_runtime.h>

typedef __bf16 bf16x8 __attribute__((ext_vector_type(8)));
typedef float f32x4 __attribute__((ext_vector_type(4)));
typedef unsigned short u16;
typedef u16 u16x8 __attribute__((ext_vector_type(8)));

__device__ __forceinline__ u16 f32_to_bf16_rne(float f) {
    union { float f; unsigned u; } cv; cv.f = f;
    unsigned u = cv.u;
    return (u16)((u + 0x7FFFu + ((u >> 16) & 1u)) >> 16);
}

// ---- repack w into bf16, k-order = koff*64 + c ----
// w2[o*512 + koff*64 + c] = bf16(w[o*512 + c*8 + koff])
__global__ void repack_w_kernel(const float* __restrict__ w, u16* __restrict__ w2) {
    int i = blockIdx.x * 256 + threadIdx.x;   // 65536 total
    int o = i >> 9;
    int r = i & 511;
    int koff = r >> 6;
    int c = r & 63;
    w2[i] = f32_to_bf16_rne(w[(o << 9) + (c << 3) + koff]);
}

// LDS x tile: xs[(kd*3+kh)*33 + w][c], c-innermost so lane's 8 consecutive
// k (= 8 consecutive c) are one ds_read_b128. Row stride 72 elems = 144 B
// (16B-aligned, 36 banks -> +4 banks/lane -> balanced 8-phase b128 reads).
#define XS_ROW 72

__global__ __launch_bounds__(256) void conv_mfma_kernel(
    const float* __restrict__ x, const u16* __restrict__ w2, float* __restrict__ out) {

    __shared__ __align__(16) u16 xs[6 * 33 * XS_ROW];   // 28512 B

    const int tid = threadIdx.x;
    const int bid = blockIdx.x;
    const int hy0 = (bid & 15) << 1;    // 2 output h-rows per block
    const int dz  = (bid >> 4) & 31;
    const int b   = bid >> 9;

    // ---- stage x tile: x[b][c][dz+kd][hy0+kh][0..32], kd 0..1, kh 0..2 ----
    const float* xb = x + (size_t)b * 64 * 35937;      // 33^3 = 35937
    for (int i = tid; i < 384 * 33; i += 256) {
        int w   = i % 33;
        int r   = i / 33;      // r = kh3*64 + c
        int c   = r & 63;
        int kh3 = r >> 6;      // 0..5
        int kd  = kh3 >= 3 ? 1 : 0;
        int kh  = kh3 - kd * 3;
        float f = xb[c * 35937 + (dz + kd) * 1089 + (hy0 + kh) * 33 + w];
        xs[(kh3 * 33 + w) * XS_ROW + c] = f32_to_bf16_rne(f);
    }
    __syncthreads();

    const int lane = tid & 63;
    const int ln   = lane & 15;
    const int g    = lane >> 4;
    const int n0w  = (tid >> 6) << 5;   // wave id * 32 = wave's o-base

    f32x4 acc[2][4];
#pragma unroll
    for (int nf = 0; nf < 2; ++nf)
#pragma unroll
        for (int mf = 0; mf < 4; ++mf)
            acc[nf][mf] = (f32x4){0.f, 0.f, 0.f, 0.f};

    const int cg = g << 3;

    // K-loop: k = koff*64 + cb*32 + (g*8 + j). No barriers inside.
#pragma unroll
    for (int koff = 0; koff < 8; ++koff) {
        const int kd = koff >> 2, kh = (koff >> 1) & 1, kw = koff & 1;
#pragma unroll
        for (int cb = 0; cb < 2; ++cb) {
            const int cbase = (cb << 5) + cg;
            bf16x8 wf[2], xf[4];
#pragma unroll
            for (int nf = 0; nf < 2; ++nf) {
                const u16* p = w2 + (((n0w + (nf << 4) + ln) << 9) + (koff << 6) + cbase);
                wf[nf] = __builtin_bit_cast(bf16x8, *reinterpret_cast<const u16x8*>(p));
            }
#pragma unroll
            for (int mf = 0; mf < 4; ++mf) {
                const int row = (kd * 3 + (mf >> 1) + kh) * 33 + ((mf & 1) << 4) + ln + kw;
                const u16* p = &xs[row * XS_ROW + cbase];
                xf[mf] = __builtin_bit_cast(bf16x8, *reinterpret_cast<const u16x8*>(p));
            }
            // D = W * Xpatch: rows = o (coalesced-store side), cols = m
#pragma unroll
            for (int nf = 0; nf < 2; ++nf)
#pragma unroll
                for (int mf = 0; mf < 4; ++mf)
                    acc[nf][mf] = __builtin_amdgcn_mfma_f32_16x16x32_bf16(
                        wf[nf], xf[mf], acc[nf][mf], 0, 0, 0);
        }
    }

    // ---- epilogue: out[b][n][dz][hy0+hrow][wx] = (y+1)^2 ----
    // C/D layout: col = lane&15 (-> m), row = (lane>>4)*4 + reg (-> n)
    float* ob = out + ((size_t)b * 128) * 32768 + (dz << 10) + (hy0 << 5);
#pragma unroll
    for (int nf = 0; nf < 2; ++nf)
#pragma unroll
        for (int mf = 0; mf < 4; ++mf) {
            const int wx   = ((mf & 1) << 4) + ln;
            const int hrow = mf >> 1;
            float* o2 = ob + (hrow << 5) + wx;
#pragma unroll
            for (int r = 0; r < 4; ++r) {
                const int n = n0w + (nf << 4) + (g << 2) + r;
                float v = acc[nf][mf][r] + 1.0f;
                o2[(size_t)n << 15] = v * v;
            }
        }
}

extern "C" void kernel_launch(void* const* d_in, const int* in_sizes, int n_in,
                              void* d_out, int out_size, void* d_ws, size_t ws_size,
                              hipStream_t stream) {
    const float* x = (const float*)d_in[0];
    const float* w = (const float*)d_in[1];
    float* out = (float*)d_out;
    u16* w2 = (u16*)d_ws;   // needs 131072 B

    repack_w_kernel<<<256, 256, 0, stream>>>(w, w2);
    conv_mfma_kernel<<<2048, 256, 0, stream>>>(x, w2, out);
}

// Round 2
// 49.014 us; speedup vs baseline: 1.3363x; 1.3363x over previous
//
#include <hip/hip_runtime.h>

typedef __bf16 bf16x8 __attribute__((ext_vector_type(8)));
typedef float f32x4 __attribute__((ext_vector_type(4)));
typedef unsigned short u16;
typedef unsigned int u32;
typedef u32 u32x4 __attribute__((ext_vector_type(4)));
typedef u16 u16x8 __attribute__((ext_vector_type(8)));

__device__ __forceinline__ u16 f32_to_bf16_rne(float f) {
    union { float f; unsigned u; } cv; cv.f = f;
    unsigned u = cv.u;
    return (u16)((u + 0x7FFFu + ((u >> 16) & 1u)) >> 16);
}

__device__ __forceinline__ u32 cvt_pk_bf16(float lo, float hi) {
    u32 r;
    asm("v_cvt_pk_bf16_f32 %0, %1, %2" : "=v"(r) : "v"(lo), "v"(hi));
    return r;
}

// ---- repack w into bf16, fragment-contiguous order ----
// w3[(((koff*2+cb)*128 + o)*4 + g)*8 + j] = bf16(w[o*512 + c*8 + koff]),
//   c = cb*32 + g*8 + j.  A wave's wf load (fixed koff,cb,nf; lane = g*16+ln)
//   then reads a fully-dense 1KB contiguous block (16x 64B segments, 4 lanes each).
__global__ void repack_w_kernel(const float* __restrict__ w, u16* __restrict__ w3) {
    int e = blockIdx.x * 256 + threadIdx.x;   // 65536 total
    int j    = e & 7;
    int g    = (e >> 3) & 3;
    int o    = (e >> 5) & 127;
    int cb   = (e >> 12) & 1;
    int koff = (e >> 13) & 7;
    int c = (cb << 5) + (g << 3) + j;
    w3[e] = f32_to_bf16_rne(w[(o << 9) + (c << 3) + koff]);
}

// LDS x tile: xs[(kd*3+kh)*33 + w][c], c innermost. Row stride 72 elems =
// 144 B: b128 reads with lane->row stride 1 are 2-way-per-phase = conflict-free.
#define XS_ROW 72

__global__ __launch_bounds__(256, 4) void conv_mfma_kernel(
    const float* __restrict__ x, const u16* __restrict__ w3, float* __restrict__ out) {

    __shared__ __align__(16) u16 xs[6 * 33 * XS_ROW];   // 28512 B

    const int tid = threadIdx.x;
    const int bid = blockIdx.x;
    const int hy0 = (bid & 15) << 1;    // 2 output h-rows per block
    const int dz  = (bid >> 4) & 31;
    const int b   = bid >> 9;

    // ---- stage x tile: 8 consecutive c per thread -> 8 coalesced dword loads,
    // 4x v_cvt_pk_bf16_f32, 1x ds_write_b128 ----
    const float* xb = x + (size_t)b * 64 * 35937;      // 33^3 = 35937
    for (int i = tid; i < 1584; i += 256) {            // 6 kh3 * 8 q * 33 w
        int w   = i % 33;
        int t   = i / 33;      // t = kh3*8 + q
        int q   = t & 7;
        int kh3 = t >> 3;      // 0..5
        int kd  = kh3 >= 3 ? 1 : 0;
        int kh  = kh3 - kd * 3;
        const float* p = xb + (size_t)(q << 3) * 35937 + (dz + kd) * 1089 + (hy0 + kh) * 33 + w;
        float f0 = p[0],          f1 = p[35937],     f2 = p[2 * 35937], f3 = p[3 * 35937];
        float f4 = p[4 * 35937],  f5 = p[5 * 35937], f6 = p[6 * 35937], f7 = p[7 * 35937];
        u32x4 v;
        v[0] = cvt_pk_bf16(f0, f1);
        v[1] = cvt_pk_bf16(f2, f3);
        v[2] = cvt_pk_bf16(f4, f5);
        v[3] = cvt_pk_bf16(f6, f7);
        *reinterpret_cast<u32x4*>(&xs[(kh3 * 33 + w) * XS_ROW + (q << 3)]) = v;
    }
    __syncthreads();

    const int lane = tid & 63;
    const int ln   = lane & 15;
    const int g    = lane >> 4;
    const int n0w  = (tid >> 6) << 5;   // wave id * 32 = wave's o-base

    f32x4 acc[2][4];
#pragma unroll
    for (int nf = 0; nf < 2; ++nf)
#pragma unroll
        for (int mf = 0; mf < 4; ++mf)
            acc[nf][mf] = (f32x4){0.f, 0.f, 0.f, 0.f};

    // K-loop restructured for ILP: per (cb,kd) group, batch-load wf[2][4]
    // (8 contiguous 1KB global b128) and per-kw xf[3][2] (6 LDS b128),
    // then 16 MFMAs per kw. k = koff*64 + cb*32 + g*8 + j.
#pragma unroll
    for (int cb = 0; cb < 2; ++cb) {
        const int cbase = (cb << 5) + (g << 3);
#pragma unroll
        for (int kd = 0; kd < 2; ++kd) {
            bf16x8 wf[2][4];
#pragma unroll
            for (int nf = 0; nf < 2; ++nf)
#pragma unroll
                for (int kk = 0; kk < 4; ++kk) {
                    const int koff = (kd << 2) + kk;
                    const u16* p = w3 + (size_t)((((koff << 1) + cb) << 7)
                                   + n0w + (nf << 4) + ln) * 32 + (g << 3);
                    wf[nf][kk] = __builtin_bit_cast(bf16x8, *reinterpret_cast<const u16x8*>(p));
                }
#pragma unroll
            for (int kw = 0; kw < 2; ++kw) {
                bf16x8 xf[3][2];
#pragma unroll
                for (int hh = 0; hh < 3; ++hh)
#pragma unroll
                    for (int wh = 0; wh < 2; ++wh) {
                        const int row = (kd * 3 + hh) * 33 + (wh << 4) + ln + kw;
                        xf[hh][wh] = __builtin_bit_cast(bf16x8,
                            *reinterpret_cast<const u16x8*>(&xs[row * XS_ROW + cbase]));
                    }
#pragma unroll
                for (int kh = 0; kh < 2; ++kh)
#pragma unroll
                    for (int nf = 0; nf < 2; ++nf)
#pragma unroll
                        for (int mf = 0; mf < 4; ++mf)
                            acc[nf][mf] = __builtin_amdgcn_mfma_f32_16x16x32_bf16(
                                wf[nf][(kh << 1) + kw], xf[(mf >> 1) + kh][mf & 1],
                                acc[nf][mf], 0, 0, 0);
            }
        }
    }

    // ---- epilogue: out[b][n][dz][hy0+hrow][wx] = (y+1)^2 ----
    // C/D layout: col = lane&15 (-> m), row = (lane>>4)*4 + reg (-> n = o)
    float* ob = out + ((size_t)b * 128) * 32768 + (dz << 10) + (hy0 << 5);
#pragma unroll
    for (int nf = 0; nf < 2; ++nf)
#pragma unroll
        for (int mf = 0; mf < 4; ++mf) {
            const int wx   = ((mf & 1) << 4) + ln;
            const int hrow = mf >> 1;
            float* o2 = ob + (hrow << 5) + wx;
#pragma unroll
            for (int r = 0; r < 4; ++r) {
                const int n = n0w + (nf << 4) + (g << 2) + r;
                float v = acc[nf][mf][r] + 1.0f;
                o2[(size_t)n << 15] = v * v;
            }
        }
}

extern "C" void kernel_launch(void* const* d_in, const int* in_sizes, int n_in,
                              void* d_out, int out_size, void* d_ws, size_t ws_size,
                              hipStream_t stream) {
    const float* x = (const float*)d_in[0];
    const float* w = (const float*)d_in[1];
    float* out = (float*)d_out;
    u16* w3 = (u16*)d_ws;   // 131072 B

    repack_w_kernel<<<256, 256, 0, stream>>>(w, w3);
    conv_mfma_kernel<<<2048, 256, 0, stream>>>(x, w3, out);
}

// Round 3
// 45.870 us; speedup vs baseline: 1.4279x; 1.0685x over previous
//
#include <hip/hip_runtime.h>

typedef __bf16 bf16x8 __attribute__((ext_vector_type(8)));
typedef float f32x4 __attribute__((ext_vector_type(4)));
typedef unsigned short u16;
typedef unsigned int u32;
typedef u32 u32x4 __attribute__((ext_vector_type(4)));
typedef u16 u16x8 __attribute__((ext_vector_type(8)));

__device__ __forceinline__ u16 f32_to_bf16_rne(float f) {
    union { float f; unsigned u; } cv; cv.f = f;
    unsigned u = cv.u;
    return (u16)((u + 0x7FFFu + ((u >> 16) & 1u)) >> 16);
}

__device__ __forceinline__ u32 cvt_pk_bf16(float lo, float hi) {
    u32 r;
    asm("v_cvt_pk_bf16_f32 %0, %1, %2" : "=v"(r) : "v"(lo), "v"(hi));
    return r;
}

// ---- repack w into bf16, fragment-contiguous order ----
// w3[(((koff*2+cb)*128 + o)*4 + g)*8 + j] = bf16(w[o*512 + c*8 + koff]),
//   c = cb*32 + g*8 + j.  A wave's wf load (fixed koff,cb,nf; lane = g*16+ln)
//   reads a fully-dense 1KB contiguous block.
__global__ void repack_w_kernel(const float* __restrict__ w, u16* __restrict__ w3) {
    int e = blockIdx.x * 256 + threadIdx.x;   // 65536 total
    int j    = e & 7;
    int g    = (e >> 3) & 3;
    int o    = (e >> 5) & 127;
    int cb   = (e >> 12) & 1;
    int koff = (e >> 13) & 7;
    int c = (cb << 5) + (g << 3) + j;
    w3[e] = f32_to_bf16_rne(w[(o << 9) + (c << 3) + koff]);
}

// LDS x tile: xs[(kd*3+kh)*33 + w][c], c innermost. Row stride 72 elems =
// 144 B -> b128 fragment reads are 2-way-per-phase = effectively free.
#define XS_ROW 72

__global__ __launch_bounds__(256, 4) void conv_mfma_kernel(
    const float* __restrict__ x, const u16* __restrict__ w3, float* __restrict__ out) {

    __shared__ __align__(16) u16 xs[6 * 33 * XS_ROW];   // 28512 B

    const int tid = threadIdx.x;
    const int bid = blockIdx.x;
    const int hy0 = (bid & 15) << 1;    // 2 output h-rows per block
    const int dz  = (bid >> 4) & 31;
    const int b   = bid >> 9;

    // ---- stage x tile, FIXED trip count + phase split so all 56 global
    // loads issue before any consumer: one latency drain instead of six.
    // item i -> (kh3 = (i/33)>>3, q = (i/33)&7, w = i%33); 8 floats of
    // consecutive c = q*8..q*8+7 each. 1584 items = 6*256 + 48.
    const float* xb = x + (size_t)b * 64 * 35937;      // 33^3 = 35937

    float f[7][8];
#pragma unroll
    for (int it = 0; it < 7; ++it) {
        if (it == 6 && tid >= 48) continue;
        const int i = tid + (it << 8);
        int w   = i % 33;
        int t   = i / 33;
        int q   = t & 7;
        int kh3 = t >> 3;      // 0..5
        int kd  = kh3 >= 3 ? 1 : 0;
        int kh  = kh3 - kd * 3;
        const float* p = xb + (size_t)(q << 3) * 35937 + (dz + kd) * 1089 + (hy0 + kh) * 33 + w;
#pragma unroll
        for (int j = 0; j < 8; ++j) f[it][j] = p[(size_t)j * 35937];
    }
#pragma unroll
    for (int it = 0; it < 7; ++it) {
        if (it == 6 && tid >= 48) continue;
        const int i = tid + (it << 8);
        int w   = i % 33;
        int t   = i / 33;
        int q   = t & 7;
        int kh3 = t >> 3;
        u32x4 v;
        v[0] = cvt_pk_bf16(f[it][0], f[it][1]);
        v[1] = cvt_pk_bf16(f[it][2], f[it][3]);
        v[2] = cvt_pk_bf16(f[it][4], f[it][5]);
        v[3] = cvt_pk_bf16(f[it][6], f[it][7]);
        *reinterpret_cast<u32x4*>(&xs[(kh3 * 33 + w) * XS_ROW + (q << 3)]) = v;
    }
    __syncthreads();

    const int lane = tid & 63;
    const int ln   = lane & 15;
    const int g    = lane >> 4;
    const int n0w  = (tid >> 6) << 5;   // wave id * 32 = wave's o-base

    f32x4 acc[2][4];
#pragma unroll
    for (int nf = 0; nf < 2; ++nf)
#pragma unroll
        for (int mf = 0; mf < 4; ++mf)
            acc[nf][mf] = (f32x4){0.f, 0.f, 0.f, 0.f};

    // K-loop: per (cb,kd) group, batch-load wf[2][4] (8 contiguous 1KB global
    // b128) and per-kw xf[3][2] (6 LDS b128), then 16 MFMAs per kw.
    // k = koff*64 + cb*32 + g*8 + j.
#pragma unroll
    for (int cb = 0; cb < 2; ++cb) {
        const int cbase = (cb << 5) + (g << 3);
#pragma unroll
        for (int kd = 0; kd < 2; ++kd) {
            bf16x8 wf[2][4];
#pragma unroll
            for (int nf = 0; nf < 2; ++nf)
#pragma unroll
                for (int kk = 0; kk < 4; ++kk) {
                    const int koff = (kd << 2) + kk;
                    const u16* p = w3 + (size_t)((((koff << 1) + cb) << 7)
                                   + n0w + (nf << 4) + ln) * 32 + (g << 3);
                    wf[nf][kk] = __builtin_bit_cast(bf16x8, *reinterpret_cast<const u16x8*>(p));
                }
#pragma unroll
            for (int kw = 0; kw < 2; ++kw) {
                bf16x8 xf[3][2];
#pragma unroll
                for (int hh = 0; hh < 3; ++hh)
#pragma unroll
                    for (int wh = 0; wh < 2; ++wh) {
                        const int row = (kd * 3 + hh) * 33 + (wh << 4) + ln + kw;
                        xf[hh][wh] = __builtin_bit_cast(bf16x8,
                            *reinterpret_cast<const u16x8*>(&xs[row * XS_ROW + cbase]));
                    }
#pragma unroll
                for (int kh = 0; kh < 2; ++kh)
#pragma unroll
                    for (int nf = 0; nf < 2; ++nf)
#pragma unroll
                        for (int mf = 0; mf < 4; ++mf)
                            acc[nf][mf] = __builtin_amdgcn_mfma_f32_16x16x32_bf16(
                                wf[nf][(kh << 1) + kw], xf[(mf >> 1) + kh][mf & 1],
                                acc[nf][mf], 0, 0, 0);
            }
        }
    }

    // ---- epilogue: out[b][n][dz][hy0+hrow][wx] = (y+1)^2 ----
    // C/D layout: col = lane&15 (-> m), row = (lane>>4)*4 + reg (-> n = o)
    float* ob = out + ((size_t)b * 128) * 32768 + (dz << 10) + (hy0 << 5);
#pragma unroll
    for (int nf = 0; nf < 2; ++nf)
#pragma unroll
        for (int mf = 0; mf < 4; ++mf) {
            const int wx   = ((mf & 1) << 4) + ln;
            const int hrow = mf >> 1;
            float* o2 = ob + (hrow << 5) + wx;
#pragma unroll
            for (int r = 0; r < 4; ++r) {
                const int n = n0w + (nf << 4) + (g << 2) + r;
                float v = acc[nf][mf][r] + 1.0f;
                o2[(size_t)n << 15] = v * v;
            }
        }
}

extern "C" void kernel_launch(void* const* d_in, const int* in_sizes, int n_in,
                              void* d_out, int out_size, void* d_ws, size_t ws_size,
                              hipStream_t stream) {
    const float* x = (const float*)d_in[0];
    const float* w = (const float*)d_in[1];
    float* out = (float*)d_out;
    u16* w3 = (u16*)d_ws;   // 131072 B

    repack_w_kernel<<<256, 256, 0, stream>>>(w, w3);
    conv_mfma_kernel<<<2048, 256, 0, stream>>>(x, w3, out);
}

// Round 4
// 45.221 us; speedup vs baseline: 1.4484x; 1.0143x over previous
//
#include <hip/hip_runtime.h>

typedef __bf16 bf16x8 __attribute__((ext_vector_type(8)));
typedef float f32x4 __attribute__((ext_vector_type(4)));
typedef unsigned short u16;
typedef unsigned int u32;
typedef u32 u32x4 __attribute__((ext_vector_type(4)));
typedef u16 u16x8 __attribute__((ext_vector_type(8)));

__device__ __forceinline__ u16 f32_to_bf16_rne(float f) {
    union { float f; unsigned u; } cv; cv.f = f;
    unsigned u = cv.u;
    return (u16)((u + 0x7FFFu + ((u >> 16) & 1u)) >> 16);
}

__device__ __forceinline__ u32 cvt_pk_bf16(float lo, float hi) {
    u32 r;
    asm("v_cvt_pk_bf16_f32 %0, %1, %2" : "=v"(r) : "v"(lo), "v"(hi));
    return r;
}

// ---- repack w into bf16, fragment-contiguous order ----
// w3[(((koff*2+cb)*128 + o)*4 + g)*8 + j] = bf16(w[o*512 + c*8 + koff]),
//   c = cb*32 + g*8 + j.  A wave's wf load (fixed koff,cb,nf; lane = g*16+ln)
//   reads a fully-dense 1KB contiguous block.
__global__ void repack_w_kernel(const float* __restrict__ w, u16* __restrict__ w3) {
    int e = blockIdx.x * 256 + threadIdx.x;   // 65536 total
    int j    = e & 7;
    int g    = (e >> 3) & 3;
    int o    = (e >> 5) & 127;
    int cb   = (e >> 12) & 1;
    int koff = (e >> 13) & 7;
    int c = (cb << 5) + (g << 3) + j;
    w3[e] = f32_to_bf16_rne(w[(o << 9) + (c << 3) + koff]);
}

// LDS x tile: xs[(kd*3+kh)*33 + w][c], c innermost. Row stride 72 elems =
// 144 B -> b128 fragment reads are 2-way-per-phase = effectively free.
#define XS_ROW 72

__global__ __launch_bounds__(256, 4) void conv_mfma_kernel(
    const float* __restrict__ x, const u16* __restrict__ w3, float* __restrict__ out) {

    __shared__ __align__(16) u16 xs[6 * 33 * XS_ROW];   // 28512 B

    const int tid = threadIdx.x;
    const int bid = blockIdx.x;
    const int hy0 = (bid & 15) << 1;    // 2 output h-rows per block
    const int dz  = (bid >> 4) & 31;
    const int b   = bid >> 9;

    // ---- stage x tile. Inline-asm loads: the compiler re-fused my two
    // previous source-level phase splits (VGPR stayed 52); asm volatile
    // global_load_dword CANNOT be shrunk or re-fused, so all 56 loads issue
    // back-to-back and drain on ONE vmcnt(0) instead of ~6 serial
    // round-trips. item i -> (kh3=(i/33)>>3, q=(i/33)&7, w=i%33),
    // 8 floats of consecutive c = q*8.. each. 1584 items = 6*256 + 48.
    const float* xb = x + (size_t)b * 64 * 35937;      // 33^3 = 35937

    float f[7][8];
#pragma unroll
    for (int it = 0; it < 7; ++it) {
        if (it == 6 && tid >= 48) continue;
        const int i = tid + (it << 8);
        int w   = i % 33;
        int t   = i / 33;
        int q   = t & 7;
        int kh3 = t >> 3;      // 0..5
        int kd  = kh3 >= 3 ? 1 : 0;
        int kh  = kh3 - kd * 3;
        const float* p = xb + (size_t)(q << 3) * 35937 + (dz + kd) * 1089 + (hy0 + kh) * 33 + w;
#pragma unroll
        for (int j = 0; j < 8; ++j) {
            asm volatile("global_load_dword %0, %1, off"
                         : "=v"(f[it][j]) : "v"(p + (size_t)j * 35937));
        }
    }
    __builtin_amdgcn_sched_barrier(0);
    asm volatile("s_waitcnt vmcnt(0)" ::: "memory");
    __builtin_amdgcn_sched_barrier(0);

#pragma unroll
    for (int it = 0; it < 7; ++it) {
        if (it == 6 && tid >= 48) continue;
        const int i = tid + (it << 8);
        int w   = i % 33;
        int t   = i / 33;
        int q   = t & 7;
        int kh3 = t >> 3;
        u32x4 v;
        v[0] = cvt_pk_bf16(f[it][0], f[it][1]);
        v[1] = cvt_pk_bf16(f[it][2], f[it][3]);
        v[2] = cvt_pk_bf16(f[it][4], f[it][5]);
        v[3] = cvt_pk_bf16(f[it][6], f[it][7]);
        *reinterpret_cast<u32x4*>(&xs[(kh3 * 33 + w) * XS_ROW + (q << 3)]) = v;
    }
    __syncthreads();

    const int lane = tid & 63;
    const int ln   = lane & 15;
    const int g    = lane >> 4;
    const int n0w  = (tid >> 6) << 5;   // wave id * 32 = wave's o-base

    f32x4 acc[2][4];
#pragma unroll
    for (int nf = 0; nf < 2; ++nf)
#pragma unroll
        for (int mf = 0; mf < 4; ++mf)
            acc[nf][mf] = (f32x4){0.f, 0.f, 0.f, 0.f};

    // K-loop: per (cb,kd) group, batch-load wf[2][4] (8 contiguous 1KB global
    // b128) and per-kw xf[3][2] (6 LDS b128), then 16 MFMAs per kw.
    // k = koff*64 + cb*32 + g*8 + j.
#pragma unroll
    for (int cb = 0; cb < 2; ++cb) {
        const int cbase = (cb << 5) + (g << 3);
#pragma unroll
        for (int kd = 0; kd < 2; ++kd) {
            bf16x8 wf[2][4];
#pragma unroll
            for (int nf = 0; nf < 2; ++nf)
#pragma unroll
                for (int kk = 0; kk < 4; ++kk) {
                    const int koff = (kd << 2) + kk;
                    const u16* p = w3 + (size_t)((((koff << 1) + cb) << 7)
                                   + n0w + (nf << 4) + ln) * 32 + (g << 3);
                    wf[nf][kk] = __builtin_bit_cast(bf16x8, *reinterpret_cast<const u16x8*>(p));
                }
#pragma unroll
            for (int kw = 0; kw < 2; ++kw) {
                bf16x8 xf[3][2];
#pragma unroll
                for (int hh = 0; hh < 3; ++hh)
#pragma unroll
                    for (int wh = 0; wh < 2; ++wh) {
                        const int row = (kd * 3 + hh) * 33 + (wh << 4) + ln + kw;
                        xf[hh][wh] = __builtin_bit_cast(bf16x8,
                            *reinterpret_cast<const u16x8*>(&xs[row * XS_ROW + cbase]));
                    }
#pragma unroll
                for (int kh = 0; kh < 2; ++kh)
#pragma unroll
                    for (int nf = 0; nf < 2; ++nf)
#pragma unroll
                        for (int mf = 0; mf < 4; ++mf)
                            acc[nf][mf] = __builtin_amdgcn_mfma_f32_16x16x32_bf16(
                                wf[nf][(kh << 1) + kw], xf[(mf >> 1) + kh][mf & 1],
                                acc[nf][mf], 0, 0, 0);
            }
        }
    }

    // ---- epilogue: out[b][n][dz][hy0+hrow][wx] = (y+1)^2 ----
    // C/D layout: col = lane&15 (-> m), row = (lane>>4)*4 + reg (-> n = o)
    float* ob = out + ((size_t)b * 128) * 32768 + (dz << 10) + (hy0 << 5);
#pragma unroll
    for (int nf = 0; nf < 2; ++nf)
#pragma unroll
        for (int mf = 0; mf < 4; ++mf) {
            const int wx   = ((mf & 1) << 4) + ln;
            const int hrow = mf >> 1;
            float* o2 = ob + (hrow << 5) + wx;
#pragma unroll
            for (int r = 0; r < 4; ++r) {
                const int n = n0w + (nf << 4) + (g << 2) + r;
                float v = acc[nf][mf][r] + 1.0f;
                o2[(size_t)n << 15] = v * v;
            }
        }
}

extern "C" void kernel_launch(void* const* d_in, const int* in_sizes, int n_in,
                              void* d_out, int out_size, void* d_ws, size_t ws_size,
                              hipStream_t stream) {
    const float* x = (const float*)d_in[0];
    const float* w = (const float*)d_in[1];
    float* out = (float*)d_out;
    u16* w3 = (u16*)d_ws;   // 131072 B

    repack_w_kernel<<<256, 256, 0, stream>>>(w, w3);
    conv_mfma_kernel<<<2048, 256, 0, stream>>>(x, w3, out);
}